// Round 6
// baseline (700.890 us; speedup 1.0000x reference)
//
#include <hip/hip_runtime.h>
#include <hip/hip_bf16.h>
#include <math.h>

// OLMoE sparse MoE block: E=32, K=4, H=2048, F=1024, T=1024 tokens.
#define NE 32
#define NK 4
#define NH 2048
#define NF 1024
#define NT 1024

#define BM 128
#define MAXTILES 64  // sum_e ceil(n_e/BM) <= 32 + 4096/128 = 64

typedef __attribute__((ext_vector_type(8))) short short8;
typedef __attribute__((ext_vector_type(4))) float f32x4;

// Workspace layout (bytes); total ~46 MB
static constexpr size_t OFF_CNT = 0;                               // int cnt[32]
static constexpr size_t OFF_ENT = 1024;                            // int entries[32][1024]
static constexpr size_t OFF_WTK = 1024 + 32 * 1024 * 4;            // float w_tk[4096]
static constexpr size_t OFF_TIL = 200704;                          // int n_tiles; int tiles[MAXTILES]
static constexpr size_t OFF_XB  = 262144;                          // bf16 xb[1024][2048] (4 MB)
static constexpr size_t OFF_ACT = OFF_XB + (size_t)NT * NH * 2;    // bf16 act[4096][1024] (8 MB)
static constexpr size_t OFF_YP  = OFF_ACT + (size_t)NT * NK * NF * 2;  // f32 yp[4096][2048] (32 MB)

// ---------------------------------------------------------------------------
__device__ inline unsigned bfbits(float f) {
  return (unsigned)__builtin_bit_cast(unsigned short, __float2bfloat16(f));
}
__device__ inline unsigned pkbf(float lo, float hi) {
  return bfbits(lo) | (bfbits(hi) << 16);
}

// ---------------------------------------------------------------------------
// Kernel 1: router. One block per token: 32 logits -> softmax -> top-4,
// append to expert lists; also emit bf16 copy of x into ws (xb).
// ---------------------------------------------------------------------------
__global__ __launch_bounds__(256) void router_kernel(
    const float* __restrict__ x, const float* __restrict__ gate_w,
    float* __restrict__ logits_out, int* __restrict__ cnt,
    int* __restrict__ entries, float* __restrict__ w_tk,
    unsigned short* __restrict__ xb) {
  __shared__ float xs[NH];
  __shared__ float logits_s[NE];
  const int t = blockIdx.x;
  const int tid = threadIdx.x;

  for (int i = tid; i < NH / 4; i += 256) {
    *reinterpret_cast<float4*>(&xs[i * 4]) =
        *reinterpret_cast<const float4*>(&x[(size_t)t * NH + i * 4]);
  }
  __syncthreads();

  // bf16 copy of this token's row (each thread packs 8 elements)
  {
    unsigned u[4];
#pragma unroll
    for (int j = 0; j < 4; ++j)
      u[j] = pkbf(xs[tid * 8 + 2 * j], xs[tid * 8 + 2 * j + 1]);
    *reinterpret_cast<uint4*>(&xb[(size_t)t * NH + tid * 8]) =
        make_uint4(u[0], u[1], u[2], u[3]);
  }

  const int wave = tid >> 6, lane = tid & 63;
  for (int ei = 0; ei < 8; ++ei) {
    const int e = wave * 8 + ei;
    const float* gw = gate_w + (size_t)e * NH;
    float s = 0.f;
    for (int h = lane; h < NH; h += 64) s += xs[h] * gw[h];
#pragma unroll
    for (int off = 32; off >= 1; off >>= 1) s += __shfl_xor(s, off, 64);
    if (lane == 0) logits_s[e] = s;
  }
  __syncthreads();

  if (wave == 0) {
    float v = (lane < NE) ? logits_s[lane] : -INFINITY;
    if (lane < NE) logits_out[(size_t)t * NE + lane] = v;
    float m = v;
#pragma unroll
    for (int off = 32; off >= 1; off >>= 1) m = fmaxf(m, __shfl_xor(m, off, 64));
    float ex = (lane < NE) ? expf(v - m) : 0.f;
    float sum = ex;
#pragma unroll
    for (int off = 32; off >= 1; off >>= 1) sum += __shfl_xor(sum, off, 64);
    float pv = (lane < NE) ? (ex / sum) : -1.f;
    for (int k = 0; k < NK; ++k) {
      float bv = pv;
      int bi = lane;
#pragma unroll
      for (int off = 32; off >= 1; off >>= 1) {
        float ov = __shfl_xor(bv, off, 64);
        int oi = __shfl_xor(bi, off, 64);
        if (ov > bv || (ov == bv && oi < bi)) { bv = ov; bi = oi; }
      }
      if (lane == 0) {
        int pos = atomicAdd(&cnt[bi], 1);
        entries[bi * NT + pos] = t * NK + k;
        w_tk[t * NK + k] = bv;
      }
      if (lane == bi) pv = -1.f;
    }
  }
}

// ---------------------------------------------------------------------------
// Kernel 1b: compact (expert, rowtile) pairs into a dense tile table.
// ---------------------------------------------------------------------------
__global__ __launch_bounds__(64) void build_tiles(
    const int* __restrict__ cnt, int* __restrict__ tile_hdr) {
  const int lane = threadIdx.x;
  int c = (lane < NE) ? cnt[lane] : 0;
  int nt = (c + BM - 1) / BM;
  int pre = nt;
#pragma unroll
  for (int d = 1; d < 32; d <<= 1) {
    int v = __shfl_up(pre, d, 64);
    if (lane >= d) pre += v;
  }
  int start = pre - nt;
  if (lane < NE) {
    for (int i = 0; i < nt; ++i) tile_hdr[1 + start + i] = (lane << 4) | i;
  }
  if (lane == NE - 1) tile_hdr[0] = pre;  // n_tiles
}

// ---------------------------------------------------------------------------
// Kernel 2: gate+up MFMA GEMM + SwiGLU. Tile 128(pairs) x 32(f), K=2048.
// 256 threads = 4 waves (2m x 2n); wave tile 64m x 16n (4 mf x 1 nf).
// NO LDS staging, NO barriers in the K-loop: A fragments load bf16 direct
// from xb (L2-resident); B fragments load 16 strided fp32 per matrix per
// step direct to regs, bf16-packed in-reg. Distance-1 double slot for B
// (named arrays -> registers). grid = (NF/32=32, MAXTILES).
// ---------------------------------------------------------------------------
__global__ __launch_bounds__(256) void phase1_mfma(
    const unsigned short* __restrict__ xb, const float* __restrict__ wg,
    const float* __restrict__ wu, const int* __restrict__ tile_hdr,
    const int* __restrict__ entries, const int* __restrict__ cnt,
    unsigned short* __restrict__ act) {
  const int s = blockIdx.y;
  if (s >= tile_hdr[0]) return;
  const int packed = tile_hdr[1 + s];
  const int e = packed >> 4, rt = packed & 15;
  const int n_e = cnt[e];
  const int f0 = blockIdx.x * 32;

  __shared__ int pair_s[BM];
  const int tid = threadIdx.x;
  if (tid < BM) {
    int idx = rt * BM + tid;
    pair_s[tid] = (idx < n_e) ? entries[e * NT + idx] : -1;
  }
  __syncthreads();  // only barrier in the kernel

  const int lane = tid & 63, wid = tid >> 6;
  const int wm = (wid >> 1) * 64, wn = (wid & 1) * 16;
  const int lm = lane & 15, lkg = lane >> 4, lk = lkg * 8;

  // A sources: row = wm + mf*16 + lm
  const unsigned short* aptr[4];
#pragma unroll
  for (int mf = 0; mf < 4; ++mf) {
    int p = pair_s[wm + mf * 16 + lm];
    int tok = (p >= 0) ? (p >> 2) : 0;
    aptr[mf] = xb + (size_t)tok * NH + lk;
  }

  // B sources: col n = f0 + wn + lm, rows k = k0 + kc*32 + lk + j
  const float* gbase = wg + (size_t)e * NH * NF + f0 + wn + lm;
  const float* ubase = wu + (size_t)e * NH * NF + f0 + wn + lm;

  f32x4 accg[4], accu[4];
#pragma unroll
  for (int i = 0; i < 4; ++i) {
    accg[i] = (f32x4)(0.f);
    accu[i] = (f32x4)(0.f);
  }

  float ga[16], ua[16], gb[16], ub[16];  // two named B slots

  auto loadB = [&](int k0, float (&g)[16], float (&u)[16]) {
#pragma unroll
    for (int kc = 0; kc < 2; ++kc)
#pragma unroll
      for (int j = 0; j < 8; ++j) {
        const size_t off = (size_t)(k0 + kc * 32 + lk + j) * NF;
        g[kc * 8 + j] = gbase[off];
        u[kc * 8 + j] = ubase[off];
      }
  };
  auto step = [&](int k0, const float (&g)[16], const float (&u)[16]) {
#pragma unroll
    for (int kc = 0; kc < 2; ++kc) {
      short8 a_[4];
#pragma unroll
      for (int mf = 0; mf < 4; ++mf)
        a_[mf] = *reinterpret_cast<const short8*>(aptr[mf] + k0 + kc * 32);
      uint4 vg, vu;
      vg.x = pkbf(g[kc * 8 + 0], g[kc * 8 + 1]);
      vg.y = pkbf(g[kc * 8 + 2], g[kc * 8 + 3]);
      vg.z = pkbf(g[kc * 8 + 4], g[kc * 8 + 5]);
      vg.w = pkbf(g[kc * 8 + 6], g[kc * 8 + 7]);
      vu.x = pkbf(u[kc * 8 + 0], u[kc * 8 + 1]);
      vu.y = pkbf(u[kc * 8 + 2], u[kc * 8 + 3]);
      vu.z = pkbf(u[kc * 8 + 4], u[kc * 8 + 5]);
      vu.w = pkbf(u[kc * 8 + 6], u[kc * 8 + 7]);
      const short8 bg = __builtin_bit_cast(short8, vg);
      const short8 bu = __builtin_bit_cast(short8, vu);
#pragma unroll
      for (int mf = 0; mf < 4; ++mf) {
        accg[mf] = __builtin_amdgcn_mfma_f32_16x16x32_bf16(a_[mf], bg, accg[mf], 0, 0, 0);
        accu[mf] = __builtin_amdgcn_mfma_f32_16x16x32_bf16(a_[mf], bu, accu[mf], 0, 0, 0);
      }
    }
  };

  const int NS = NH / 64;  // 32 (even)
  loadB(0, ga, ua);
  for (int t = 0; t < NS; t += 2) {
    loadB((t + 1) * 64, gb, ub);          // in flight across step t
    step(t * 64, ga, ua);
    if (t + 2 < NS) loadB((t + 2) * 64, ga, ua);  // in flight across step t+1
    step((t + 1) * 64, gb, ub);
  }

  // epilogue: silu(g)*u -> act bf16. D layout: col=lane&15, row=(lane>>4)*4+r.
  const int rbase = wm + lkg * 4;
#pragma unroll
  for (int mf = 0; mf < 4; ++mf) {
#pragma unroll
    for (int r = 0; r < 4; ++r) {
      const int row = rbase + mf * 16 + r;
      const int p = pair_s[row];
      if (p < 0) continue;
      float g = accg[mf][r], u = accu[mf][r];
      float o = (g / (1.f + __expf(-g))) * u;
      act[(size_t)p * NF + f0 + wn + lm] = (unsigned short)bfbits(o);
    }
  }
}

// ---------------------------------------------------------------------------
// Kernel 3: down-proj MFMA GEMM, same barrier-free structure.
// Tile 128 x 32 over H, K=F=1024. grid = (NH/32=64, MAXTILES).
// ---------------------------------------------------------------------------
__global__ __launch_bounds__(256) void phase2_mfma(
    const unsigned short* __restrict__ act, const float* __restrict__ wd,
    const int* __restrict__ tile_hdr, const int* __restrict__ entries,
    const int* __restrict__ cnt, float* __restrict__ yp) {
  const int s = blockIdx.y;
  if (s >= tile_hdr[0]) return;
  const int packed = tile_hdr[1 + s];
  const int e = packed >> 4, rt = packed & 15;
  const int n_e = cnt[e];
  const int h0 = blockIdx.x * 32;

  __shared__ int pair_s[BM];
  const int tid = threadIdx.x;
  if (tid < BM) {
    int idx = rt * BM + tid;
    pair_s[tid] = (idx < n_e) ? entries[e * NT + idx] : -1;
  }
  __syncthreads();

  const int lane = tid & 63, wid = tid >> 6;
  const int wm = (wid >> 1) * 64, wn = (wid & 1) * 16;
  const int lm = lane & 15, lkg = lane >> 4, lk = lkg * 8;

  const unsigned short* aptr[4];
#pragma unroll
  for (int mf = 0; mf < 4; ++mf) {
    int p = pair_s[wm + mf * 16 + lm];
    int pa = (p >= 0) ? p : 0;
    aptr[mf] = act + (size_t)pa * NF + lk;
  }

  const float* dbase = wd + (size_t)e * NF * NH + h0 + wn + lm;

  f32x4 acc[4];
#pragma unroll
  for (int i = 0; i < 4; ++i) acc[i] = (f32x4)(0.f);

  float da[16], db[16];  // two named B slots

  auto loadB = [&](int k0, float (&d)[16]) {
#pragma unroll
    for (int kc = 0; kc < 2; ++kc)
#pragma unroll
      for (int j = 0; j < 8; ++j)
        d[kc * 8 + j] = dbase[(size_t)(k0 + kc * 32 + lk + j) * NH];
  };
  auto step = [&](int k0, const float (&d)[16]) {
#pragma unroll
    for (int kc = 0; kc < 2; ++kc) {
      short8 a_[4];
#pragma unroll
      for (int mf = 0; mf < 4; ++mf)
        a_[mf] = *reinterpret_cast<const short8*>(aptr[mf] + k0 + kc * 32);
      uint4 vd;
      vd.x = pkbf(d[kc * 8 + 0], d[kc * 8 + 1]);
      vd.y = pkbf(d[kc * 8 + 2], d[kc * 8 + 3]);
      vd.z = pkbf(d[kc * 8 + 4], d[kc * 8 + 5]);
      vd.w = pkbf(d[kc * 8 + 6], d[kc * 8 + 7]);
      const short8 bd = __builtin_bit_cast(short8, vd);
#pragma unroll
      for (int mf = 0; mf < 4; ++mf)
        acc[mf] = __builtin_amdgcn_mfma_f32_16x16x32_bf16(a_[mf], bd, acc[mf], 0, 0, 0);
    }
  };

  const int NS = NF / 64;  // 16 (even)
  loadB(0, da);
  for (int t = 0; t < NS; t += 2) {
    loadB((t + 1) * 64, db);
    step(t * 64, da);
    if (t + 2 < NS) loadB((t + 2) * 64, da);
    step((t + 1) * 64, db);
  }

  const int rbase = wm + lkg * 4;
#pragma unroll
  for (int mf = 0; mf < 4; ++mf) {
#pragma unroll
    for (int r = 0; r < 4; ++r) {
      const int row = rbase + mf * 16 + r;
      const int p = pair_s[row];
      if (p < 0) continue;
      yp[(size_t)p * NH + h0 + wn + lm] = acc[mf][r];
    }
  }
}

// ---------------------------------------------------------------------------
// Kernel 4: combine. out[t,h] = sum_k w_tk[t*4+k] * yp[t*4+k][h]. float4,
// deterministic (fixed k order).
// ---------------------------------------------------------------------------
__global__ __launch_bounds__(256) void combine_kernel(
    const float* __restrict__ yp, const float* __restrict__ w_tk,
    float* __restrict__ out) {
  const size_t idx = (size_t)blockIdx.x * 256 + threadIdx.x;  // over NT*NH/4
  const int t = (int)(idx >> 9);           // NH/4 = 512 vec4 per token
  const int h4 = (int)(idx & 511) * 4;
  float4 s = make_float4(0.f, 0.f, 0.f, 0.f);
#pragma unroll
  for (int k = 0; k < NK; ++k) {
    const float w = w_tk[t * NK + k];
    const float4 v = *reinterpret_cast<const float4*>(
        &yp[((size_t)(t * NK + k)) * NH + h4]);
    s.x += w * v.x; s.y += w * v.y; s.z += w * v.z; s.w += w * v.w;
  }
  *reinterpret_cast<float4*>(&out[(size_t)t * NH + h4]) = s;
}

// ---------------------------------------------------------------------------
extern "C" void kernel_launch(void* const* d_in, const int* in_sizes, int n_in,
                              void* d_out, int out_size, void* d_ws,
                              size_t ws_size, hipStream_t stream) {
  const float* x      = (const float*)d_in[0];
  const float* gate_w = (const float*)d_in[1];
  const float* wg     = (const float*)d_in[2];
  const float* wu     = (const float*)d_in[3];
  const float* wd     = (const float*)d_in[4];

  float* out        = (float*)d_out;
  float* logits_out = (float*)d_out + (size_t)NT * NH;

  char* ws = (char*)d_ws;
  int* cnt            = (int*)(ws + OFF_CNT);
  int* entries        = (int*)(ws + OFF_ENT);
  float* w_tk         = (float*)(ws + OFF_WTK);
  int* tile_hdr       = (int*)(ws + OFF_TIL);
  unsigned short* xb  = (unsigned short*)(ws + OFF_XB);
  unsigned short* act = (unsigned short*)(ws + OFF_ACT);
  float* yp           = (float*)(ws + OFF_YP);

  hipMemsetAsync(ws, 0, 1024, stream);  // zero expert counters

  router_kernel<<<NT, 256, 0, stream>>>(x, gate_w, logits_out, cnt, entries, w_tk, xb);
  build_tiles<<<1, 64, 0, stream>>>(cnt, tile_hdr);
  phase1_mfma<<<dim3(NF / 32, MAXTILES), 256, 0, stream>>>(xb, wg, wu, tile_hdr, entries, cnt, act);
  phase2_mfma<<<dim3(NH / 32, MAXTILES), 256, 0, stream>>>(act, wd, tile_hdr, entries, cnt, yp);
  combine_kernel<<<(NT * NH / 4) / 256, 256, 0, stream>>>(yp, w_tk, out);
}

// Round 7
// 371.809 us; speedup vs baseline: 1.8851x; 1.8851x over previous
//
#include <hip/hip_runtime.h>
#include <hip/hip_bf16.h>
#include <math.h>

// OLMoE sparse MoE block: E=32, K=4, H=2048, F=1024, T=1024 tokens.
#define NE 32
#define NK 4
#define NH 2048
#define NF 1024
#define NT 1024

#define BM 128
#define BN 64
#define BK 64
#define MAXTILES 64

typedef __attribute__((ext_vector_type(8))) short short8;
typedef __attribute__((ext_vector_type(4))) float f32x4;

#define ASMV(s) asm volatile(s ::: "memory")

// Workspace layout (bytes); total ~46 MB
static constexpr size_t OFF_CNT = 0;
static constexpr size_t OFF_ENT = 1024;
static constexpr size_t OFF_WTK = 1024 + 32 * 1024 * 4;
static constexpr size_t OFF_TIL = 200704;
static constexpr size_t OFF_XB  = 262144;
static constexpr size_t OFF_ACT = OFF_XB + (size_t)NT * NH * 2;
static constexpr size_t OFF_YP  = OFF_ACT + (size_t)NT * NK * NF * 2;

// ---------------------------------------------------------------------------
__device__ inline unsigned bfbits(float f) {
  return (unsigned)__builtin_bit_cast(unsigned short, __float2bfloat16(f));
}
__device__ inline unsigned pkbf(float lo, float hi) {
  return bfbits(lo) | (bfbits(hi) << 16);
}
// XOR-swizzled element index for a [rows][64] bf16 tile (row stride 128 B).
__device__ inline int swz(int r, int k) {
  int b = (r << 7) | (k << 1);
  return (b ^ ((r & 7) << 4)) >> 1;
}
// async global->LDS 16B: per-lane global src, wave-uniform LDS base + lane*16
__device__ inline void gload16(const unsigned short* g, void* l) {
  __builtin_amdgcn_global_load_lds(
      (const __attribute__((address_space(1))) unsigned int*)g,
      (__attribute__((address_space(3))) unsigned int*)l, 16, 0, 0);
}

// ---------------------------------------------------------------------------
// Kernel 1: router (unchanged, validated).
// ---------------------------------------------------------------------------
__global__ __launch_bounds__(256) void router_kernel(
    const float* __restrict__ x, const float* __restrict__ gate_w,
    float* __restrict__ logits_out, int* __restrict__ cnt,
    int* __restrict__ entries, float* __restrict__ w_tk,
    unsigned short* __restrict__ xb) {
  __shared__ float xs[NH];
  __shared__ float logits_s[NE];
  const int t = blockIdx.x;
  const int tid = threadIdx.x;

  for (int i = tid; i < NH / 4; i += 256) {
    *reinterpret_cast<float4*>(&xs[i * 4]) =
        *reinterpret_cast<const float4*>(&x[(size_t)t * NH + i * 4]);
  }
  __syncthreads();

  {
    unsigned u[4];
#pragma unroll
    for (int j = 0; j < 4; ++j)
      u[j] = pkbf(xs[tid * 8 + 2 * j], xs[tid * 8 + 2 * j + 1]);
    *reinterpret_cast<uint4*>(&xb[(size_t)t * NH + tid * 8]) =
        make_uint4(u[0], u[1], u[2], u[3]);
  }

  const int wave = tid >> 6, lane = tid & 63;
  for (int ei = 0; ei < 8; ++ei) {
    const int e = wave * 8 + ei;
    const float* gw = gate_w + (size_t)e * NH;
    float s = 0.f;
    for (int h = lane; h < NH; h += 64) s += xs[h] * gw[h];
#pragma unroll
    for (int off = 32; off >= 1; off >>= 1) s += __shfl_xor(s, off, 64);
    if (lane == 0) logits_s[e] = s;
  }
  __syncthreads();

  if (wave == 0) {
    float v = (lane < NE) ? logits_s[lane] : -INFINITY;
    if (lane < NE) logits_out[(size_t)t * NE + lane] = v;
    float m = v;
#pragma unroll
    for (int off = 32; off >= 1; off >>= 1) m = fmaxf(m, __shfl_xor(m, off, 64));
    float ex = (lane < NE) ? expf(v - m) : 0.f;
    float sum = ex;
#pragma unroll
    for (int off = 32; off >= 1; off >>= 1) sum += __shfl_xor(sum, off, 64);
    float pv = (lane < NE) ? (ex / sum) : -1.f;
    for (int k = 0; k < NK; ++k) {
      float bv = pv;
      int bi = lane;
#pragma unroll
      for (int off = 32; off >= 1; off >>= 1) {
        float ov = __shfl_xor(bv, off, 64);
        int oi = __shfl_xor(bi, off, 64);
        if (ov > bv || (ov == bv && oi < bi)) { bv = ov; bi = oi; }
      }
      if (lane == 0) {
        int pos = atomicAdd(&cnt[bi], 1);
        entries[bi * NT + pos] = t * NK + k;
        w_tk[t * NK + k] = bv;
      }
      if (lane == bi) pv = -1.f;
    }
  }
}

// ---------------------------------------------------------------------------
// Kernel 1b: compact (expert, rowtile) tile table (unchanged).
// ---------------------------------------------------------------------------
__global__ __launch_bounds__(64) void build_tiles(
    const int* __restrict__ cnt, int* __restrict__ tile_hdr) {
  const int lane = threadIdx.x;
  int c = (lane < NE) ? cnt[lane] : 0;
  int nt = (c + BM - 1) / BM;
  int pre = nt;
#pragma unroll
  for (int d = 1; d < 32; d <<= 1) {
    int v = __shfl_up(pre, d, 64);
    if (lane >= d) pre += v;
  }
  int start = pre - nt;
  if (lane < NE) {
    for (int i = 0; i < nt; ++i) tile_hdr[1 + start + i] = (lane << 4) | i;
  }
  if (lane == NE - 1) tile_hdr[0] = pre;
}

// ---------------------------------------------------------------------------
// Kernel 2: gate+up MFMA GEMM + SwiGLU. Round-3 skeleton with counted-vmcnt
// single-barrier pipeline: A via gload_lds (distance 1), B via regs
// (distance 2, two named slots) -> cvt -> swizzled LDS dbuf.
// Tile 128 x 64, BK=64, 4 waves. grid = (NF/64=16, MAXTILES).
// ---------------------------------------------------------------------------
__global__ __launch_bounds__(256) void phase1_mfma(
    const unsigned short* __restrict__ xb, const float* __restrict__ wg,
    const float* __restrict__ wu, const int* __restrict__ tile_hdr,
    const int* __restrict__ entries, const int* __restrict__ cnt,
    unsigned short* __restrict__ act) {
  const int s = blockIdx.y;
  if (s >= tile_hdr[0]) return;
  const int packed = tile_hdr[1 + s];
  const int e = packed >> 4, rt = packed & 15;
  const int n_e = cnt[e];
  const int f0 = blockIdx.x * BN;

  __shared__ unsigned short As[2][BM * BK];   // 2 x 16 KB
  __shared__ unsigned short Bgs[2][BN * BK];  // 2 x 8 KB
  __shared__ unsigned short Bus[2][BN * BK];  // 2 x 8 KB
  __shared__ int pair_s[BM];

  const int tid = threadIdx.x;
  if (tid < BM) {
    int idx = rt * BM + tid;
    pair_s[tid] = (idx < n_e) ? entries[e * NT + idx] : -1;
  }
  __syncthreads();

  const int lane = tid & 63, wid = tid >> 6;

  // A DMA sources (inverse-swizzled per-lane k, validated round 3)
  const int klane = ((lane & 7) ^ (lane >> 3)) * 8;
  const unsigned short* asrc[4];
#pragma unroll
  for (int j = 0; j < 4; ++j) {
    int row = wid * 32 + j * 8 + (lane >> 3);
    int p = pair_s[row];
    int tok = (p >= 0) ? (p >> 2) : 0;
    asrc[j] = xb + (size_t)tok * NH + klane;
  }

  // B staging roles: lane = n column (64), wid = k-quarter (16 k each)
  const int bn = lane, bq = wid;
  const float* bgb = wg + (size_t)e * NH * NF + f0 + bn;
  const float* bub = wu + (size_t)e * NH * NF + f0 + bn;
  float g0[16], u0[16], g1[16], u1[16];  // two named B slots (distance 2)

  const int wm = (wid >> 1) * 64, wn = (wid & 1) * 32;
  const int lm = lane & 15, lk = (lane >> 4) * 8;

  f32x4 accg[4][2], accu[4][2];
#pragma unroll
  for (int i = 0; i < 4; ++i)
#pragma unroll
    for (int j = 0; j < 2; ++j) {
      accg[i][j] = (f32x4)(0.f);
      accu[i][j] = (f32x4)(0.f);
    }

  auto issueA = [&](int k0, int b) {
#pragma unroll
    for (int j = 0; j < 4; ++j)
      gload16(asrc[j] + k0, (char*)&As[b][0] + wid * 4096 + j * 1024);
  };
  auto loadB = [&](int k0, float (&g)[16], float (&u)[16]) {
    const int kb = k0 + bq * 16;
#pragma unroll
    for (int i = 0; i < 16; ++i) {
      g[i] = bgb[(size_t)(kb + i) * NF];
      u[i] = bub[(size_t)(kb + i) * NF];
    }
  };
  auto storeB = [&](const float (&g)[16], const float (&u)[16], int b) {
    const int kb = bq * 16;
#pragma unroll
    for (int q = 0; q < 4; ++q) {
      uint2 ug, uu;
      ug.x = pkbf(g[q * 4 + 0], g[q * 4 + 1]);
      ug.y = pkbf(g[q * 4 + 2], g[q * 4 + 3]);
      uu.x = pkbf(u[q * 4 + 0], u[q * 4 + 1]);
      uu.y = pkbf(u[q * 4 + 2], u[q * 4 + 3]);
      *reinterpret_cast<uint2*>(&Bgs[b][swz(bn, kb + q * 4)]) = ug;
      *reinterpret_cast<uint2*>(&Bus[b][swz(bn, kb + q * 4)]) = uu;
    }
  };
  auto compute = [&](int c) {
#pragma unroll
    for (int kc = 0; kc < 2; ++kc) {
      short8 a[4], bg[2], bu[2];
#pragma unroll
      for (int mf = 0; mf < 4; ++mf)
        a[mf] = *reinterpret_cast<const short8*>(
            &As[c][swz(wm + mf * 16 + lm, kc * 32 + lk)]);
#pragma unroll
      for (int nf = 0; nf < 2; ++nf) {
        bg[nf] = *reinterpret_cast<const short8*>(
            &Bgs[c][swz(wn + nf * 16 + lm, kc * 32 + lk)]);
        bu[nf] = *reinterpret_cast<const short8*>(
            &Bus[c][swz(wn + nf * 16 + lm, kc * 32 + lk)]);
      }
#pragma unroll
      for (int mf = 0; mf < 4; ++mf)
#pragma unroll
        for (int nf = 0; nf < 2; ++nf) {
          accg[mf][nf] = __builtin_amdgcn_mfma_f32_16x16x32_bf16(a[mf], bg[nf], accg[mf][nf], 0, 0, 0);
          accu[mf][nf] = __builtin_amdgcn_mfma_f32_16x16x32_bf16(a[mf], bu[nf], accu[mf][nf], 0, 0, 0);
        }
    }
  };

  const int NS = NH / BK;  // 32
  // ---- prologue ----
  loadB(0, g0, u0);                    // B(0), 32 loads
  issueA(0, 0);                        // A(0) DMA, 4
  ASMV("s_waitcnt vmcnt(4)");          // B(0) done (A(0) still flying)
  storeB(g0, u0, 0);
  loadB(BK, g0, u0);                   // B(1) -> slot0, 32 loads
  ASMV("s_waitcnt vmcnt(32)");         // A(0) done (B(1) still flying)
  ASMV("s_waitcnt lgkmcnt(0)");
  __builtin_amdgcn_s_barrier();
  __builtin_amdgcn_sched_barrier(0);

  // ---- main loop: iters t (even, buf0) and t+1 (odd, buf1), t <= NS-4 ----
  for (int t = 0; t < NS - 2; t += 2) {
    // even: compute buf0; slot0 holds B(t+1)
    loadB((t + 2) * BK, g1, u1);       // B(t+2) -> slot1
    issueA((t + 1) * BK, 1);           // A(t+1) -> buf1
    compute(0);
    storeB(g0, u0, 1);                 // compiler waits slot0 only
    ASMV("s_waitcnt vmcnt(32)");       // A(t+1) done; B(t+2) still flying
    ASMV("s_waitcnt lgkmcnt(0)");
    __builtin_amdgcn_s_barrier();
    __builtin_amdgcn_sched_barrier(0);
    // odd: compute buf1; slot1 holds B(t+2)
    loadB((t + 3) * BK, g0, u0);       // B(t+3) -> slot0
    issueA((t + 2) * BK, 0);           // A(t+2) -> buf0
    compute(1);
    storeB(g1, u1, 0);
    ASMV("s_waitcnt vmcnt(32)");       // A(t+2) done; B(t+3) still flying
    ASMV("s_waitcnt lgkmcnt(0)");
    __builtin_amdgcn_s_barrier();
    __builtin_amdgcn_sched_barrier(0);
  }
  // ---- tail: t = NS-2 (buf0), NS-1 (buf1); no more prefetch ----
  issueA((NS - 1) * BK, 1);            // A(NS-1) -> buf1
  compute(0);
  storeB(g0, u0, 1);                   // B(NS-1) (loaded in last odd body)
  ASMV("s_waitcnt vmcnt(0)");
  ASMV("s_waitcnt lgkmcnt(0)");
  __builtin_amdgcn_s_barrier();
  __builtin_amdgcn_sched_barrier(0);
  compute(1);

  // epilogue: silu(g)*u -> act bf16. D layout: col=lane&15, row=(lane>>4)*4+r.
  const int rbase = wm + (lane >> 4) * 4;
#pragma unroll
  for (int mf = 0; mf < 4; ++mf) {
#pragma unroll
    for (int r = 0; r < 4; ++r) {
      const int row = rbase + mf * 16 + r;
      const int p = pair_s[row];
      if (p < 0) continue;
#pragma unroll
      for (int nf = 0; nf < 2; ++nf) {
        float g = accg[mf][nf][r], u = accu[mf][nf][r];
        float o = (g / (1.f + __expf(-g))) * u;
        act[(size_t)p * NF + f0 + wn + nf * 16 + lm] = (unsigned short)bfbits(o);
      }
    }
  }
}

// ---------------------------------------------------------------------------
// Kernel 3: down-proj MFMA GEMM, same counted-vmcnt pipeline. K=F=1024.
// grid = (NH/64=32, MAXTILES).
// ---------------------------------------------------------------------------
__global__ __launch_bounds__(256) void phase2_mfma(
    const unsigned short* __restrict__ act, const float* __restrict__ wd,
    const int* __restrict__ tile_hdr, const int* __restrict__ entries,
    const int* __restrict__ cnt, float* __restrict__ yp) {
  const int s = blockIdx.y;
  if (s >= tile_hdr[0]) return;
  const int packed = tile_hdr[1 + s];
  const int e = packed >> 4, rt = packed & 15;
  const int n_e = cnt[e];
  const int h0 = blockIdx.x * BN;

  __shared__ unsigned short As[2][BM * BK];  // 2 x 16 KB
  __shared__ unsigned short Bs[2][BN * BK];  // 2 x 8 KB
  __shared__ int pair_s[BM];

  const int tid = threadIdx.x;
  if (tid < BM) {
    int idx = rt * BM + tid;
    pair_s[tid] = (idx < n_e) ? entries[e * NT + idx] : -1;
  }
  __syncthreads();

  const int lane = tid & 63, wid = tid >> 6;

  const int klane = ((lane & 7) ^ (lane >> 3)) * 8;
  const unsigned short* asrc[4];
#pragma unroll
  for (int j = 0; j < 4; ++j) {
    int row = wid * 32 + j * 8 + (lane >> 3);
    int p = pair_s[row];
    int pa = (p >= 0) ? p : 0;
    asrc[j] = act + (size_t)pa * NF + klane;
  }

  const int bn = lane, bq = wid;
  const float* bb = wd + (size_t)e * NF * NH + h0 + bn;
  float d0[16], d1[16];

  const int wm = (wid >> 1) * 64, wn = (wid & 1) * 32;
  const int lm = lane & 15, lk = (lane >> 4) * 8;

  f32x4 acc[4][2];
#pragma unroll
  for (int i = 0; i < 4; ++i)
#pragma unroll
    for (int j = 0; j < 2; ++j) acc[i][j] = (f32x4)(0.f);

  auto issueA = [&](int k0, int b) {
#pragma unroll
    for (int j = 0; j < 4; ++j)
      gload16(asrc[j] + k0, (char*)&As[b][0] + wid * 4096 + j * 1024);
  };
  auto loadB = [&](int k0, float (&d)[16]) {
    const int kb = k0 + bq * 16;
#pragma unroll
    for (int i = 0; i < 16; ++i) d[i] = bb[(size_t)(kb + i) * NH];
  };
  auto storeB = [&](const float (&d)[16], int b) {
    const int kb = bq * 16;
#pragma unroll
    for (int q = 0; q < 4; ++q) {
      uint2 u;
      u.x = pkbf(d[q * 4 + 0], d[q * 4 + 1]);
      u.y = pkbf(d[q * 4 + 2], d[q * 4 + 3]);
      *reinterpret_cast<uint2*>(&Bs[b][swz(bn, kb + q * 4)]) = u;
    }
  };
  auto compute = [&](int c) {
#pragma unroll
    for (int kc = 0; kc < 2; ++kc) {
      short8 a[4], b2[2];
#pragma unroll
      for (int mf = 0; mf < 4; ++mf)
        a[mf] = *reinterpret_cast<const short8*>(
            &As[c][swz(wm + mf * 16 + lm, kc * 32 + lk)]);
#pragma unroll
      for (int nf = 0; nf < 2; ++nf)
        b2[nf] = *reinterpret_cast<const short8*>(
            &Bs[c][swz(wn + nf * 16 + lm, kc * 32 + lk)]);
#pragma unroll
      for (int mf = 0; mf < 4; ++mf)
#pragma unroll
        for (int nf = 0; nf < 2; ++nf)
          acc[mf][nf] = __builtin_amdgcn_mfma_f32_16x16x32_bf16(a[mf], b2[nf], acc[mf][nf], 0, 0, 0);
    }
  };

  const int NS = NF / BK;  // 16
  // prologue
  loadB(0, d0);
  issueA(0, 0);
  ASMV("s_waitcnt vmcnt(4)");
  storeB(d0, 0);
  loadB(BK, d0);
  ASMV("s_waitcnt vmcnt(16)");
  ASMV("s_waitcnt lgkmcnt(0)");
  __builtin_amdgcn_s_barrier();
  __builtin_amdgcn_sched_barrier(0);

  for (int t = 0; t < NS - 2; t += 2) {
    loadB((t + 2) * BK, d1);
    issueA((t + 1) * BK, 1);
    compute(0);
    storeB(d0, 1);
    ASMV("s_waitcnt vmcnt(16)");
    ASMV("s_waitcnt lgkmcnt(0)");
    __builtin_amdgcn_s_barrier();
    __builtin_amdgcn_sched_barrier(0);
    loadB((t + 3) * BK, d0);
    issueA((t + 2) * BK, 0);
    compute(1);
    storeB(d1, 0);
    ASMV("s_waitcnt vmcnt(16)");
    ASMV("s_waitcnt lgkmcnt(0)");
    __builtin_amdgcn_s_barrier();
    __builtin_amdgcn_sched_barrier(0);
  }
  issueA((NS - 1) * BK, 1);
  compute(0);
  storeB(d0, 1);
  ASMV("s_waitcnt vmcnt(0)");
  ASMV("s_waitcnt lgkmcnt(0)");
  __builtin_amdgcn_s_barrier();
  __builtin_amdgcn_sched_barrier(0);
  compute(1);

  const int rbase = wm + (lane >> 4) * 4;
#pragma unroll
  for (int mf = 0; mf < 4; ++mf) {
#pragma unroll
    for (int r = 0; r < 4; ++r) {
      const int row = rbase + mf * 16 + r;
      const int p = pair_s[row];
      if (p < 0) continue;
#pragma unroll
      for (int nf = 0; nf < 2; ++nf)
        yp[(size_t)p * NH + h0 + wn + nf * 16 + lm] = acc[mf][nf][r];
    }
  }
}

// ---------------------------------------------------------------------------
// Kernel 4: combine (unchanged).
// ---------------------------------------------------------------------------
__global__ __launch_bounds__(256) void combine_kernel(
    const float* __restrict__ yp, const float* __restrict__ w_tk,
    float* __restrict__ out) {
  const size_t idx = (size_t)blockIdx.x * 256 + threadIdx.x;
  const int t = (int)(idx >> 9);
  const int h4 = (int)(idx & 511) * 4;
  float4 s = make_float4(0.f, 0.f, 0.f, 0.f);
#pragma unroll
  for (int k = 0; k < NK; ++k) {
    const float w = w_tk[t * NK + k];
    const float4 v = *reinterpret_cast<const float4*>(
        &yp[((size_t)(t * NK + k)) * NH + h4]);
    s.x += w * v.x; s.y += w * v.y; s.z += w * v.z; s.w += w * v.w;
  }
  *reinterpret_cast<float4*>(&out[(size_t)t * NH + h4]) = s;
}

// ---------------------------------------------------------------------------
extern "C" void kernel_launch(void* const* d_in, const int* in_sizes, int n_in,
                              void* d_out, int out_size, void* d_ws,
                              size_t ws_size, hipStream_t stream) {
  const float* x      = (const float*)d_in[0];
  const float* gate_w = (const float*)d_in[1];
  const float* wg     = (const float*)d_in[2];
  const float* wu     = (const float*)d_in[3];
  const float* wd     = (const float*)d_in[4];

  float* out        = (float*)d_out;
  float* logits_out = (float*)d_out + (size_t)NT * NH;

  char* ws = (char*)d_ws;
  int* cnt            = (int*)(ws + OFF_CNT);
  int* entries        = (int*)(ws + OFF_ENT);
  float* w_tk         = (float*)(ws + OFF_WTK);
  int* tile_hdr       = (int*)(ws + OFF_TIL);
  unsigned short* xb  = (unsigned short*)(ws + OFF_XB);
  unsigned short* act = (unsigned short*)(ws + OFF_ACT);
  float* yp           = (float*)(ws + OFF_YP);

  hipMemsetAsync(ws, 0, 1024, stream);  // zero expert counters

  router_kernel<<<NT, 256, 0, stream>>>(x, gate_w, logits_out, cnt, entries, w_tk, xb);
  build_tiles<<<1, 64, 0, stream>>>(cnt, tile_hdr);
  phase1_mfma<<<dim3(NF / BN, MAXTILES), 256, 0, stream>>>(xb, wg, wu, tile_hdr, entries, cnt, act);
  phase2_mfma<<<dim3(NH / BN, MAXTILES), 256, 0, stream>>>(act, wd, tile_hdr, entries, cnt, yp);
  combine_kernel<<<(NT * NH / 4) / 256, 256, 0, stream>>>(yp, w_tk, out);
}